// Round 1
// baseline (356.130 us; speedup 1.0000x reference)
//
#include <hip/hip_runtime.h>

// Problem constants (from reference)
constexpr int N    = 50000;   // nodes
constexpr int E    = 800000;  // edges
constexpr int CIN  = 128;
constexpr int COUT = 64;
constexpr float SELF_LOOP_W = 2.0f;

// ---------------------------------------------------------------------------
// 1) deg[n] = 2.0 (self-loop contribution folded into init)
__global__ void deg_init_kernel(float* __restrict__ deg) {
    int i = blockIdx.x * blockDim.x + threadIdx.x;
    if (i < N) deg[i] = SELF_LOOP_W;
}

// 2) deg[col[e]] += ew[e]
__global__ void deg_scatter_kernel(const int* __restrict__ col,
                                   const float* __restrict__ ew,
                                   float* __restrict__ deg) {
    int e = blockIdx.x * blockDim.x + threadIdx.x;
    if (e < E) atomicAdd(&deg[col[e]], ew[e]);
}

// 3) deg -> dinv in place
__global__ void dinv_kernel(float* __restrict__ deg) {
    int i = blockIdx.x * blockDim.x + threadIdx.x;
    if (i < N) {
        float d = deg[i];
        deg[i] = (d > 0.f) ? rsqrtf(d) : 0.f;
    }
}

// 4) xw = x @ W   (one wave per node; lane = output channel)
__global__ __launch_bounds__(256) void xw_kernel(const float* __restrict__ x,
                                                 const float* __restrict__ W,
                                                 float* __restrict__ xw) {
    __shared__ float xs[4][CIN];
    const int wave = threadIdx.x >> 6;
    const int lane = threadIdx.x & 63;
    const int node = blockIdx.x * 4 + wave;   // grid = N/4 exactly (50000/4=12500)

    const float* xr = x + (size_t)node * CIN;
    xs[wave][lane]      = xr[lane];
    xs[wave][lane + 64] = xr[lane + 64];
    __syncthreads();

    float acc = 0.f;
    #pragma unroll
    for (int k = 0; k < CIN; ++k)
        acc += xs[wave][k] * W[k * COUT + lane];

    xw[(size_t)node * COUT + lane] = acc;
}

// 5) out = 2*dinv^2*xw + b   (WRITE — establishes out without a memset)
__global__ void self_bias_kernel(const float* __restrict__ xw,
                                 const float* __restrict__ dinv,
                                 const float* __restrict__ b,
                                 float* __restrict__ out) {
    int i = blockIdx.x * blockDim.x + threadIdx.x;
    if (i < N * COUT) {
        int n = i >> 6;
        int c = i & 63;
        float di = dinv[n];
        out[i] = SELF_LOOP_W * di * di * xw[i] + b[c];
    }
}

// 6) out[col] += dinv[row]*ew*dinv[col] * xw[row]  (one wave per edge)
__global__ __launch_bounds__(256) void edge_agg_kernel(const int* __restrict__ row,
                                                       const int* __restrict__ col,
                                                       const float* __restrict__ ew,
                                                       const float* __restrict__ dinv,
                                                       const float* __restrict__ xw,
                                                       float* __restrict__ out) {
    const int e    = blockIdx.x * 4 + (threadIdx.x >> 6);  // grid = E/4 exactly
    const int lane = threadIdx.x & 63;
    const int r = row[e];
    const int c = col[e];
    const float nrm = dinv[r] * ew[e] * dinv[c];
    atomicAdd(&out[(size_t)c * COUT + lane], nrm * xw[(size_t)r * COUT + lane]);
}

// ---------------------------------------------------------------------------
extern "C" void kernel_launch(void* const* d_in, const int* in_sizes, int n_in,
                              void* d_out, int out_size, void* d_ws, size_t ws_size,
                              hipStream_t stream) {
    const float* x  = (const float*)d_in[0];
    const int*   ei = (const int*)d_in[1];   // [2, E] int32 (JAX x64 disabled)
    const float* ew = (const float*)d_in[2];
    const float* W  = (const float*)d_in[3];
    const float* b  = (const float*)d_in[4];
    float* out = (float*)d_out;

    // workspace layout: xw [N*COUT] floats, then deg/dinv [N] floats
    float* xw  = (float*)d_ws;
    float* deg = xw + (size_t)N * COUT;

    const int* rowp = ei;       // edge_index[0] = source
    const int* colp = ei + E;   // edge_index[1] = target

    deg_init_kernel   <<<(N + 255) / 256, 256, 0, stream>>>(deg);
    deg_scatter_kernel<<<(E + 255) / 256, 256, 0, stream>>>(colp, ew, deg);
    dinv_kernel       <<<(N + 255) / 256, 256, 0, stream>>>(deg);
    xw_kernel         <<<N / 4,           256, 0, stream>>>(x, W, xw);
    self_bias_kernel  <<<(N * COUT + 255) / 256, 256, 0, stream>>>(xw, deg, b, out);
    edge_agg_kernel   <<<E / 4,           256, 0, stream>>>(rowp, colp, ew, deg, xw, out);
}